// Round 8
// baseline (472.665 us; speedup 1.0000x reference)
//
#include <hip/hip_runtime.h>

#define BB 8192
#define TT 20
#define HH 128
#define H4 512
#define KC 5
#define R 32
#define NT 1024
#define NBLK (BB/R)   // 256 blocks = 1 per CU, 16 waves each

typedef _Float16 f16;
typedef float v4f __attribute__((ext_vector_type(4)));
typedef _Float16 v8h __attribute__((ext_vector_type(8)));

// output segment offsets (elements)
#define GY_OFF (BB*TT*30)
#define GF_OFF (GY_OFF + BB*TT*15)
#define GFA_OFF (GF_OFF + BB*TT*15)

// ws offsets in f16 units
#define UMY_O   0          // U_my fp16 hi, permuted cols (65536)
#define UFF_O   65536
#define WMYH_O  131072     // W_my[:128] fp16 hi, permuted (65536)
#define WMYL_O  196608     // fp16 lo
#define WFFH_O  262144
#define WFFL_O  327680
#define WHMY_O  393216     // Wh_my hi, unpermuted (6144)
#define WHFF_O  399360     // Wh_ff hi (4096)
#define PREP_N  272384

__device__ __forceinline__ float rcp_(float x){ return __builtin_amdgcn_rcpf(x); }
__device__ __forceinline__ float sigm(float x){ return rcp_(1.0f + __expf(-x)); }
__device__ __forceinline__ float tanh_(float x){
    x = __builtin_amdgcn_fmed3f(x, -10.0f, 10.0f);
    float e = __expf(2.0f * x);
    return (e - 1.0f) * rcp_(e + 1.0f);
}

#define AM0 0.3f
#define AM1 0.1f
#define AO  0.3f

// B-frag (16x16x32): lane L holds B[k=(L>>4)*8+jj][n=L&15], jj=0..7.
// elem index e = ((c*4+q)*64 + L)*8 + jj.  U/W col-permutation: tile c -> gate=c&3,
// unit base=((c>>2)<<4), so orig col = (c&3)*128 + ((c>>2)<<4) + (L&15).
__global__ void prep_kernel(const float* __restrict__ U_my, const float* __restrict__ U_ff,
                            const float* __restrict__ W_my, const float* __restrict__ W_ff,
                            const float* __restrict__ Wh_my, const float* __restrict__ Wh_ff,
                            f16* __restrict__ ws)
{
    int t = blockIdx.x * 256 + threadIdx.x;
    if (t >= PREP_N) return;
    if (t < 131072){
        int m = t >> 16, e = t & 65535;
        int jj = e & 7, L = (e >> 3) & 63, q = (e >> 9) & 3, c = e >> 11;
        int k   = q*32 + ((L >> 4) << 3) + jj;
        int col = (c & 3)*HH + ((c >> 2) << 4) + (L & 15);
        float v = (m ? U_ff : U_my)[k*H4 + col];
        ws[(m ? UFF_O : UMY_O) + e] = (f16)v;
    } else if (t < 262144){
        int m = (t - 131072) >> 16, e = t & 65535;
        int jj = e & 7, L = (e >> 3) & 63, q = (e >> 9) & 3, c = e >> 11;
        int k   = q*32 + ((L >> 4) << 3) + jj;
        int col = (c & 3)*HH + ((c >> 2) << 4) + (L & 15);
        float v = (m ? W_ff : W_my)[k*H4 + col];
        f16 hi = (f16)v;
        f16 lo = (f16)(v - (float)hi);
        ws[(m ? WFFH_O : WMYH_O) + e] = hi;
        ws[(m ? WFFL_O : WMYL_O) + e] = lo;
    } else if (t < 262144 + 6144){
        int e = t - 262144;
        int jj = e & 7, L = (e >> 3) & 63, q = (e >> 9) & 3, c = e >> 11;   // c 0..2
        int k   = q*32 + ((L >> 4) << 3) + jj;
        int col = (c << 4) + (L & 15);
        float v = (col < 45) ? Wh_my[k*45 + col] : 0.0f;
        ws[WHMY_O + e] = (f16)v;
    } else {
        int e = t - 262144 - 6144;
        int jj = e & 7, L = (e >> 3) & 63, q = (e >> 9) & 3, c = e >> 11;   // c 0..1
        int k   = q*32 + ((L >> 4) << 3) + jj;
        int col = (c << 4) + (L & 15);
        float v = (col < 30) ? Wh_ff[k*30 + col] : 0.0f;
        ws[WHFF_O + e] = (f16)v;
    }
}

// gate nonlinearity for one rt; k-outer so each W-cond value is read ONCE per rt
template<int NC>
__device__ __forceinline__ void gates_body(
    v4f am[4], const float* __restrict__ cndp, const float* __restrict__ wcp,
    float* __restrict__ cc, f16 (* __restrict__ wr_hi)[136], f16 (* __restrict__ wr_lo)[136],
    int rt, int quad, int jcol)
{
    #pragma unroll
    for (int k = 0; k < NC; k++){
        float w0 = wcp[k*H4 + 0*HH + jcol];
        float w1 = wcp[k*H4 + 1*HH + jcol];
        float w2 = wcp[k*H4 + 2*HH + jcol];
        float w3 = wcp[k*H4 + 3*HH + jcol];
        #pragma unroll
        for (int v = 0; v < 4; v++){
            float cv = cndp[(rt*16 + quad*4 + v)*NC + k];
            am[0][v] = fmaf(cv, w0, am[0][v]);
            am[1][v] = fmaf(cv, w1, am[1][v]);
            am[2][v] = fmaf(cv, w2, am[2][v]);
            am[3][v] = fmaf(cv, w3, am[3][v]);
        }
    }
    #pragma unroll
    for (int v = 0; v < 4; v++){
        int row = rt*16 + quad*4 + v;
        float c2 = sigm(am[1][v])*cc[rt*4+v] + sigm(am[0][v])*tanh_(am[2][v]);
        cc[rt*4+v] = c2;
        float h = sigm(am[3][v])*tanh_(c2);
        f16 hi = (f16)h;
        wr_hi[row][jcol] = hi;
        wr_lo[row][jcol] = (f16)(h - (float)hi);
    }
}

__global__ __launch_bounds__(NT, 4) void decoder_kernel(
    const float* __restrict__ cond_m, const float* __restrict__ cond_y,
    const float* __restrict__ cond_f, const float* __restrict__ cond_fa,
    const float* __restrict__ state_h, const float* __restrict__ state_c,
    const float* __restrict__ W_my, const float* __restrict__ b_my,
    const float* __restrict__ W_ff, const float* __restrict__ b_ff,
    const float* __restrict__ bh_my, const float* __restrict__ bh_ff,
    const float* __restrict__ gum, const float* __restrict__ znorm,
    const f16* __restrict__ ws, float* __restrict__ out)
{
    __shared__ f16 s_hm_hi[2][R][136], s_hm_lo[2][R][136];   // double-buffered h
    __shared__ f16 s_hf_hi[2][R][136], s_hf_lo[2][R][136];
    __shared__ float s_wcm[5][H4], s_wcf[2][H4];             // cond rows of W
    __shared__ float s_r[R][76];
    __shared__ float s_c5[R][5], s_c2[R][2];
    __shared__ float s_gum[2][R][20], s_zn[2][R][5], s_nc[2][R][5];

    const int tid  = threadIdx.x;
    const int lane = tid & 63, w = tid >> 6;           // 16 waves
    const int quad = lane >> 4, l15 = lane & 15;
    const int stripe = w & 7;                          // unit stripe for this wave
    const int isMy = (w < 8);                          // waves 0-7: my-LSTM, 8-15: ff-LSTM
    const int jcol = (stripe << 4) + l15;
    const int row0 = blockIdx.x * R;

    // ---- init LDS ----
    for (int p = tid; p < R*HH; p += NT){
        int r = p >> 7, k = p & 127;
        float v = state_h[(row0 + r)*HH + k];
        f16 hi = (f16)v, lo = (f16)(v - (float)hi);
        s_hm_hi[0][r][k] = hi; s_hm_lo[0][r][k] = lo;
        s_hf_hi[0][r][k] = hi; s_hf_lo[0][r][k] = lo;
    }
    for (int p = tid; p < 5*H4; p += NT) s_wcm[p >> 9][p & 511] = W_my[(HH + (p >> 9))*H4 + (p & 511)];
    for (int p = tid; p < 2*H4; p += NT) s_wcf[p >> 9][p & 511] = W_ff[(HH + (p >> 9))*H4 + (p & 511)];
    if (tid < R){
        int b = row0 + tid;
        float m0 = cond_m[(b*TT)*2 + 0], m1 = cond_m[(b*TT)*2 + 1];
        float y0 = cond_y[b*TT], f0 = cond_f[b*TT], fa0 = cond_fa[b*TT];
        s_c5[tid][0]=m0; s_c5[tid][1]=m1; s_c5[tid][2]=y0; s_c5[tid][3]=f0; s_c5[tid][4]=fa0;
        s_c2[tid][0]=f0; s_c2[tid][1]=fa0;
    }
    // initial sampling-input prefetch for t=0 into buf 0
    for (int i = tid; i < 960; i += NT){
        if (i < 640){
            int r = i/20, rem = i - r*20, j = rem/5, k = rem - j*5;
            s_gum[0][r][rem] = gum[(j*BB + row0 + r)*KC + k];
        } else if (i < 800){
            int e = i - 640, r = e/5, k = e - r*5;
            s_zn[0][r][k] = znorm[(row0 + r)*5 + k];
        } else {
            int e = i - 800, r = e/5, k = e - r*5;
            int b = row0 + r; int tn = 1;
            float v = (k==0) ? cond_m[(b*TT + tn)*2 + 0]
                    : (k==1) ? cond_m[(b*TT + tn)*2 + 1]
                    : (k==2) ? cond_y[b*TT + tn]
                    : (k==3) ? cond_f[b*TT + tn]
                    :          cond_fa[b*TT + tn];
            s_nc[0][r][k] = v;
        }
    }

    // c-state in registers: cc[rt*4+v] -> row rt*16+quad*4+v, unit jcol (wave-exclusive)
    float cc[8];
    #pragma unroll
    for (int rt = 0; rt < 2; rt++)
        #pragma unroll
        for (int v = 0; v < 4; v++)
            cc[rt*4+v] = state_c[(row0 + rt*16 + quad*4 + v)*HH + jcol];
    __syncthreads();

    // ---- one-time: pre = enc_h @ W[:128] + b via 3-term fp16 MFMA (own LSTM only) ----
    v4f pre[4][2];
    {
        const int baseH = isMy ? WMYH_O : WFFH_O;
        const int baseL = isMy ? WMYL_O : WFFL_O;
        const float* bias = isMy ? b_my : b_ff;
        #pragma unroll
        for (int ci = 0; ci < 4; ci++){
            pre[ci][0] = (v4f){0,0,0,0}; pre[ci][1] = (v4f){0,0,0,0};
            #pragma unroll
            for (int q = 0; q < 4; q++){
                int off = (((stripe*4 + ci)*4 + q)*64 + lane)*8;
                v8h bh_ = *(const v8h*)(ws + baseH + off);
                v8h bl_ = *(const v8h*)(ws + baseL + off);
                #pragma unroll
                for (int rt = 0; rt < 2; rt++){
                    v8h ahi = *(const v8h*)&s_hm_hi[0][rt*16 + l15][q*32 + quad*8];
                    v8h alo = *(const v8h*)&s_hm_lo[0][rt*16 + l15][q*32 + quad*8];
                    pre[ci][rt] = __builtin_amdgcn_mfma_f32_16x16x32_f16(ahi, bh_, pre[ci][rt],0,0,0);
                    pre[ci][rt] = __builtin_amdgcn_mfma_f32_16x16x32_f16(ahi, bl_, pre[ci][rt],0,0,0);
                    pre[ci][rt] = __builtin_amdgcn_mfma_f32_16x16x32_f16(alo, bh_, pre[ci][rt],0,0,0);
                }
            }
            float bv = bias[ci*HH + jcol];
            #pragma unroll
            for (int rt = 0; rt < 2; rt++)
                #pragma unroll
                for (int v = 0; v < 4; v++) pre[ci][rt][v] += bv;
        }
    }

    // ---- persistent U B-fragments (own LSTM only: 64 VGPR) ----
    v8h BU[4][4];
    {
        const int ubase = isMy ? UMY_O : UFF_O;
        #pragma unroll
        for (int ci = 0; ci < 4; ci++)
            #pragma unroll
            for (int q = 0; q < 4; q++)
                BU[ci][q] = *(const v8h*)(ws + ubase + (((stripe*4 + ci)*4 + q)*64 + lane)*8);
    }

    // wave-uniform gate-phase pointers
    const float* wcp  = isMy ? &s_wcm[0][0] : &s_wcf[0][0];
    const float* cndp = isMy ? &s_c5[0][0]  : &s_c2[0][0];

    int cur = 0;
    for (int t = 0; t < TT; t++){
        const int pb = t & 1;
        const f16 (*rd_hi)[136] = isMy ? s_hm_hi[cur]   : s_hf_hi[cur];
        const f16 (*rd_lo)[136] = isMy ? s_hm_lo[cur]   : s_hf_lo[cur];
        f16 (*wr_hi)[136]       = isMy ? s_hm_hi[cur^1] : s_hf_hi[cur^1];
        f16 (*wr_lo)[136]       = isMy ? s_hm_lo[cur^1] : s_hf_lo[cur^1];

        // ===== z + gates for own LSTM, rt-split (am = 16 VGPR) =====
        #pragma unroll
        for (int rt = 0; rt < 2; rt++){
            v4f am[4];
            #pragma unroll
            for (int ci = 0; ci < 4; ci++) am[ci] = pre[ci][rt];
            #pragma unroll
            for (int q = 0; q < 4; q++){
                v8h ahi = *(const v8h*)&rd_hi[rt*16 + l15][q*32 + quad*8];
                v8h alo = *(const v8h*)&rd_lo[rt*16 + l15][q*32 + quad*8];
                #pragma unroll
                for (int ci = 0; ci < 4; ci++){
                    am[ci] = __builtin_amdgcn_mfma_f32_16x16x32_f16(ahi, BU[ci][q], am[ci],0,0,0);
                    am[ci] = __builtin_amdgcn_mfma_f32_16x16x32_f16(alo, BU[ci][q], am[ci],0,0,0);
                }
            }
            if (isMy) gates_body<5>(am, cndp, wcp, cc, wr_hi, wr_lo, rt, quad, jcol);
            else      gates_body<2>(am, cndp, wcp, cc, wr_hi, wr_lo, rt, quad, jcol);
        }
        __syncthreads();   // B1: new h visible (drains prev-step output stores)

        // ===== heads (waves 0-9, 1 rt each) / prefetch t+1 (waves 10-15) =====
        if (w < 10){
            int w5 = w >> 1, rth = w & 1;
            int hm = (w5 < 3);
            const f16 (*Hhi)[136] = hm ? s_hm_hi[cur^1] : s_hf_hi[cur^1];
            const f16 (*Hlo)[136] = hm ? s_hm_lo[cur^1] : s_hf_lo[cur^1];
            int base  = hm ? WHMY_O : WHFF_O;
            int ch    = hm ? w5 : w5 - 3;
            int ncol  = hm ? 45 : 30;
            int rbase = hm ? 0 : 45;
            const float* bh = hm ? bh_my : bh_ff;
            v4f a = (v4f){0,0,0,0};
            #pragma unroll
            for (int q = 0; q < 4; q++){
                v8h BHq = *(const v8h*)(ws + base + ((ch*4 + q)*64 + lane)*8);
                v8h ahi = *(const v8h*)&Hhi[rth*16 + l15][q*32 + quad*8];
                v8h alo = *(const v8h*)&Hlo[rth*16 + l15][q*32 + quad*8];
                a = __builtin_amdgcn_mfma_f32_16x16x32_f16(ahi, BHq, a,0,0,0);
                a = __builtin_amdgcn_mfma_f32_16x16x32_f16(alo, BHq, a,0,0,0);
            }
            int gc = ch*16 + l15;
            if (gc < ncol){
                float bias = bh[gc];
                #pragma unroll
                for (int v = 0; v < 4; v++)
                    s_r[rth*16 + quad*4 + v][rbase + gc] = a[v] + bias;
            }
        } else {
            int tp = t + 1;
            if (tp < TT){
                int pb2 = tp & 1;
                int tn2 = (tp + 1 < TT) ? tp + 1 : TT - 1;
                for (int i = tid - 640; i < 960; i += 384){
                    if (i < 640){
                        int r = i/20, rem = i - r*20, j = rem/5, k = rem - j*5;
                        s_gum[pb2][r][rem] = gum[((tp*4 + j)*BB + row0 + r)*KC + k];
                    } else if (i < 800){
                        int e = i - 640, r = e/5, k = e - r*5;
                        s_zn[pb2][r][k] = znorm[(tp*BB + row0 + r)*5 + k];
                    } else {
                        int e = i - 800, r = e/5, k = e - r*5;
                        int b = row0 + r;
                        float v = (k==0) ? cond_m[(b*TT + tn2)*2 + 0]
                                : (k==1) ? cond_m[(b*TT + tn2)*2 + 1]
                                : (k==2) ? cond_y[b*TT + tn2]
                                : (k==3) ? cond_f[b*TT + tn2]
                                :          cond_fa[b*TT + tn2];
                        s_nc[pb2][r][k] = v;
                    }
                }
            }
        }
        __syncthreads();   // B2: s_r visible

        // ===== sampling + next cond (tid<128 only — short narrow phase) =====
        if (tid < R*4){
            int r = tid >> 2, g = tid & 3;
            const float* Rr = s_r[r];
            int base = (g==0) ? 0 : (g==1) ? 30 : (g==2) ? 45 : 60;
            const float* gg = &s_gum[pb][r][g*5];
            int im = 0; float bv = Rr[base] + gg[0];
            #pragma unroll
            for (int k = 1; k < KC; k++){
                float v = Rr[base+k] + gg[k];
                if (v > bv){ bv = v; im = k; }
            }
            if (g == 0){
                float z1 = s_zn[pb][r][0], z2 = s_zn[pb][r][1];
                float rv   = tanh_(Rr[25 + im]);
                float slon = Rr[5 + im]  + __expf(Rr[10 + im]) * z1;
                float slat = Rr[15 + im] + __expf(Rr[20 + im]) *
                             (rv*z1 + sqrtf(fmaxf(0.f, 1.f - rv*rv))*z2);
                float nm0 = s_nc[pb][r][0], nm1 = s_nc[pb][r][1];
                s_c5[r][0] = (fabsf(slon - nm0) < AM0) ? slon : nm0;
                s_c5[r][1] = (fabsf(slat - nm1) < AM1) ? slat : nm1;
            } else if (g == 1){
                float sy = Rr[35 + im] + __expf(Rr[40 + im]) * s_zn[pb][r][2];
                float ny = s_nc[pb][r][2];
                s_c5[r][2] = (fabsf(sy - ny) < AO) ? sy : ny;
            } else if (g == 2){
                float sf = Rr[50 + im] + __expf(Rr[55 + im]) * s_zn[pb][r][3];
                float nf = s_nc[pb][r][3];
                float cf = (fabsf(sf - nf) < AO) ? sf : nf;
                s_c5[r][3] = cf; s_c2[r][0] = cf;
            } else {
                float sfa = Rr[65 + im] + __expf(Rr[70 + im]) * s_zn[pb][r][4];
                float nfa = s_nc[pb][r][4];
                float cfa = (fabsf(sfa - nfa) < AO) ? sfa : nfa;
                s_c5[r][4] = cfa; s_c2[r][1] = cfa;
            }
        }
        __syncthreads();   // B3: s_c5/s_c2 visible before gates(t+1)

        // ===== outputs (all 16 waves, 2 rows each, fused local softmax) =====
        // No trailing barrier: stores overlap z+gates(t+1), drain at B1(t+1).
        #pragma unroll
        for (int it = 0; it < 2; it++){
            int r = (w << 1) | it;
            const float* Rr = s_r[r];
            int b = row0 + r;
            #pragma unroll
            for (int half = 0; half < 2; half++){
                int c = lane + half*64;   // 64 lanes cover 75 cols in 2 passes
                if (c < 75){
                    int seg = (c < 30) ? 0 : (c < 45) ? 1 : (c < 60) ? 2 : 3;
                    int q2  = (seg==0) ? c : (seg==1) ? c-30 : (seg==2) ? c-45 : c-60;
                    int sb  = (seg==0) ? 0 : (seg==1) ? 30 : (seg==2) ? 45 : 60;
                    float x = Rr[sb + q2];
                    float v;
                    if (q2 < 5){
                        float x0=Rr[sb],x1=Rr[sb+1],x2=Rr[sb+2],x3=Rr[sb+3],x4=Rr[sb+4];
                        float m = fmaxf(fmaxf(fmaxf(x0,x1), fmaxf(x2,x3)), x4);
                        float s = __expf(x0-m)+__expf(x1-m)+__expf(x2-m)+__expf(x3-m)+__expf(x4-m);
                        v = __expf(x-m)*rcp_(s);
                    } else if (seg == 0){
                        v = (q2<10)? x : (q2<15)? __expf(x) : (q2<20)? x : (q2<25)? __expf(x) : tanh_(x);
                    } else {
                        v = (q2<10)? x : __expf(x);
                    }
                    int dst = (seg==0) ? (b*TT+t)*30 + q2
                            : (seg==1) ? GY_OFF  + (b*TT+t)*15 + q2
                            : (seg==2) ? GF_OFF  + (b*TT+t)*15 + q2
                            :            GFA_OFF + (b*TT+t)*15 + q2;
                    out[dst] = v;
                }
            }
        }
        cur ^= 1;
    }
}

extern "C" void kernel_launch(void* const* d_in, const int* in_sizes, int n_in,
                              void* d_out, int out_size, void* d_ws, size_t ws_size,
                              hipStream_t stream)
{
    (void)in_sizes; (void)n_in; (void)ws_size; (void)out_size;
    const float* cond_m  = (const float*)d_in[0];
    const float* cond_y  = (const float*)d_in[1];
    const float* cond_f  = (const float*)d_in[2];
    const float* cond_fa = (const float*)d_in[3];
    const float* state_h = (const float*)d_in[4];
    const float* state_c = (const float*)d_in[5];
    const float* W_my    = (const float*)d_in[6];
    const float* U_my    = (const float*)d_in[7];
    const float* b_my    = (const float*)d_in[8];
    const float* W_ff    = (const float*)d_in[9];
    const float* U_ff    = (const float*)d_in[10];
    const float* b_ff    = (const float*)d_in[11];
    const float* Wh_my   = (const float*)d_in[12];
    const float* bh_my   = (const float*)d_in[13];
    const float* Wh_ff   = (const float*)d_in[14];
    const float* bh_ff   = (const float*)d_in[15];
    const float* gum     = (const float*)d_in[16];
    const float* znorm   = (const float*)d_in[17];
    f16* ws = (f16*)d_ws;
    float* out = (float*)d_out;

    prep_kernel<<<(PREP_N + 255)/256, 256, 0, stream>>>(U_my, U_ff, W_my, W_ff, Wh_my, Wh_ff, ws);
    decoder_kernel<<<NBLK, NT, 0, stream>>>(
        cond_m, cond_y, cond_f, cond_fa, state_h, state_c,
        W_my, b_my, W_ff, b_ff, bh_my, bh_ff, gum, znorm, ws, out);
}

// Round 9
// 447.751 us; speedup vs baseline: 1.0556x; 1.0556x over previous
//
#include <hip/hip_runtime.h>

#define BB 8192
#define TT 20
#define HH 128
#define H4 512
#define KC 5
#define R 32
#define NT 1024
#define NBLK (BB/R)   // 256 blocks = 1 per CU, 16 waves each

typedef _Float16 f16;
typedef float v4f __attribute__((ext_vector_type(4)));
typedef _Float16 v8h __attribute__((ext_vector_type(8)));

// output segment offsets (elements)
#define GY_OFF (BB*TT*30)
#define GF_OFF (GY_OFF + BB*TT*15)
#define GFA_OFF (GF_OFF + BB*TT*15)

// ws offsets in f16 units
#define UMY_O   0          // U_my fp16 hi, permuted cols (65536)
#define UFF_O   65536
#define WMYH_O  131072     // W_my[:128] fp16 hi, permuted (65536)
#define WMYL_O  196608     // fp16 lo
#define WFFH_O  262144
#define WFFL_O  327680
#define WHMY_O  393216     // Wh_my hi, unpermuted (6144)
#define WHFF_O  399360     // Wh_ff hi (4096)
#define PREP_N  272384

__device__ __forceinline__ float rcp_(float x){ return __builtin_amdgcn_rcpf(x); }
__device__ __forceinline__ float sigm(float x){ return rcp_(1.0f + __expf(-x)); }
__device__ __forceinline__ float tanh_(float x){
    x = __builtin_amdgcn_fmed3f(x, -10.0f, 10.0f);
    float e = __expf(2.0f * x);
    return (e - 1.0f) * rcp_(e + 1.0f);
}

#define AM0 0.3f
#define AM1 0.1f
#define AO  0.3f

// B-frag (16x16x32): lane L holds B[k=(L>>4)*8+jj][n=L&15], jj=0..7.
// elem index e = ((c*4+q)*64 + L)*8 + jj.  U/W col-permutation: tile c -> gate=c&3,
// unit base=((c>>2)<<4), so orig col = (c&3)*128 + ((c>>2)<<4) + (L&15).
__global__ void prep_kernel(const float* __restrict__ U_my, const float* __restrict__ U_ff,
                            const float* __restrict__ W_my, const float* __restrict__ W_ff,
                            const float* __restrict__ Wh_my, const float* __restrict__ Wh_ff,
                            f16* __restrict__ ws)
{
    int t = blockIdx.x * 256 + threadIdx.x;
    if (t >= PREP_N) return;
    if (t < 131072){
        int m = t >> 16, e = t & 65535;
        int jj = e & 7, L = (e >> 3) & 63, q = (e >> 9) & 3, c = e >> 11;
        int k   = q*32 + ((L >> 4) << 3) + jj;
        int col = (c & 3)*HH + ((c >> 2) << 4) + (L & 15);
        float v = (m ? U_ff : U_my)[k*H4 + col];
        ws[(m ? UFF_O : UMY_O) + e] = (f16)v;
    } else if (t < 262144){
        int m = (t - 131072) >> 16, e = t & 65535;
        int jj = e & 7, L = (e >> 3) & 63, q = (e >> 9) & 3, c = e >> 11;
        int k   = q*32 + ((L >> 4) << 3) + jj;
        int col = (c & 3)*HH + ((c >> 2) << 4) + (L & 15);
        float v = (m ? W_ff : W_my)[k*H4 + col];
        f16 hi = (f16)v;
        f16 lo = (f16)(v - (float)hi);
        ws[(m ? WFFH_O : WMYH_O) + e] = hi;
        ws[(m ? WFFL_O : WMYL_O) + e] = lo;
    } else if (t < 262144 + 6144){
        int e = t - 262144;
        int jj = e & 7, L = (e >> 3) & 63, q = (e >> 9) & 3, c = e >> 11;   // c 0..2
        int k   = q*32 + ((L >> 4) << 3) + jj;
        int col = (c << 4) + (L & 15);
        float v = (col < 45) ? Wh_my[k*45 + col] : 0.0f;
        ws[WHMY_O + e] = (f16)v;
    } else {
        int e = t - 262144 - 6144;
        int jj = e & 7, L = (e >> 3) & 63, q = (e >> 9) & 3, c = e >> 11;   // c 0..1
        int k   = q*32 + ((L >> 4) << 3) + jj;
        int col = (c << 4) + (L & 15);
        float v = (col < 30) ? Wh_ff[k*30 + col] : 0.0f;
        ws[WHFF_O + e] = (f16)v;
    }
}

__global__ __launch_bounds__(NT, 4) void decoder_kernel(
    const float* __restrict__ cond_m, const float* __restrict__ cond_y,
    const float* __restrict__ cond_f, const float* __restrict__ cond_fa,
    const float* __restrict__ state_h, const float* __restrict__ state_c,
    const float* __restrict__ W_my, const float* __restrict__ b_my,
    const float* __restrict__ W_ff, const float* __restrict__ b_ff,
    const float* __restrict__ bh_my, const float* __restrict__ bh_ff,
    const float* __restrict__ gum, const float* __restrict__ znorm,
    const f16* __restrict__ ws, float* __restrict__ out)
{
    __shared__ f16 s_hm_hi[2][R][136], s_hm_lo[2][R][136];   // double-buffered h (hi+lo kept: heads need lo)
    __shared__ f16 s_hf_hi[2][R][136], s_hf_lo[2][R][136];
    __shared__ float s_r[R][76];
    __shared__ float s_red[R][8];
    __shared__ float s_c5p[R][8], s_c2p[R][4];               // padded cond for vector reads
    __shared__ float s_gum[2][R][20], s_zn[2][R][5], s_nc[2][R][5];

    const int tid  = threadIdx.x;
    const int lane = tid & 63, w = tid >> 6;           // 16 waves
    const int quad = lane >> 4, l15 = lane & 15;
    const int stripe = w & 7;                          // unit stripe for this wave
    const int isMy = (w < 8);                          // waves 0-7: my-LSTM, 8-15: ff-LSTM
    const int jcol = (stripe << 4) + l15;
    const int row0 = blockIdx.x * R;

    // ---- init LDS ----
    for (int p = tid; p < R*HH; p += NT){
        int r = p >> 7, k = p & 127;
        float v = state_h[(row0 + r)*HH + k];
        f16 hi = (f16)v, lo = (f16)(v - (float)hi);
        s_hm_hi[0][r][k] = hi; s_hm_lo[0][r][k] = lo;
        s_hf_hi[0][r][k] = hi; s_hf_lo[0][r][k] = lo;
    }
    if (tid < R){
        int b = row0 + tid;
        float m0 = cond_m[(b*TT)*2 + 0], m1 = cond_m[(b*TT)*2 + 1];
        float y0 = cond_y[b*TT], f0 = cond_f[b*TT], fa0 = cond_fa[b*TT];
        s_c5p[tid][0]=m0; s_c5p[tid][1]=m1; s_c5p[tid][2]=y0; s_c5p[tid][3]=f0; s_c5p[tid][4]=fa0;
        s_c2p[tid][0]=f0; s_c2p[tid][1]=fa0;
    }
    // initial sampling-input prefetch for t=0 into buf 0
    for (int i = tid; i < 960; i += NT){
        if (i < 640){
            int r = i/20, rem = i - r*20, j = rem/5, k = rem - j*5;
            s_gum[0][r][rem] = gum[(j*BB + row0 + r)*KC + k];
        } else if (i < 800){
            int e = i - 640, r = e/5, k = e - r*5;
            s_zn[0][r][k] = znorm[(row0 + r)*5 + k];
        } else {
            int e = i - 800, r = e/5, k = e - r*5;
            int b = row0 + r; int tn = 1;
            float v = (k==0) ? cond_m[(b*TT + tn)*2 + 0]
                    : (k==1) ? cond_m[(b*TT + tn)*2 + 1]
                    : (k==2) ? cond_y[b*TT + tn]
                    : (k==3) ? cond_f[b*TT + tn]
                    :          cond_fa[b*TT + tn];
            s_nc[0][r][k] = v;
        }
    }

    // c-state in registers: cc[rt*4+v] -> row rt*16+quad*4+v, unit jcol (wave-exclusive)
    float cc[8];
    #pragma unroll
    for (int rt = 0; rt < 2; rt++)
        #pragma unroll
        for (int v = 0; v < 4; v++)
            cc[rt*4+v] = state_c[(row0 + rt*16 + quad*4 + v)*HH + jcol];

    // ---- W-cond gate weights -> registers (t-invariant): wreg[k][gate] ----
    v4f wreg[5];
    {
        const float* Wsrc = isMy ? W_my : W_ff;
        const int nk = isMy ? 5 : 2;
        #pragma unroll
        for (int k = 0; k < 5; k++){
            if (k < nk){
                wreg[k][0] = Wsrc[(HH + k)*H4 + 0*HH + jcol];
                wreg[k][1] = Wsrc[(HH + k)*H4 + 1*HH + jcol];
                wreg[k][2] = Wsrc[(HH + k)*H4 + 2*HH + jcol];
                wreg[k][3] = Wsrc[(HH + k)*H4 + 3*HH + jcol];
            } else wreg[k] = (v4f){0,0,0,0};
        }
    }

    // ---- heads constants (t-invariant), waves 0-9 ----
    v8h BH[4]; float hbias = 0.f;
    int hm = 0, rth = 0, gc = 0, ncol = 0, rbase = 0;
    if (w < 10){
        int w5 = w >> 1; rth = w & 1; hm = (w5 < 3);
        int base  = hm ? WHMY_O : WHFF_O;
        int ch    = hm ? w5 : w5 - 3;
        ncol  = hm ? 45 : 30;
        rbase = hm ? 0 : 45;
        gc = ch*16 + l15;
        const float* bh = hm ? bh_my : bh_ff;
        if (gc < ncol) hbias = bh[gc];
        #pragma unroll
        for (int q = 0; q < 4; q++)
            BH[q] = *(const v8h*)(ws + base + ((ch*4 + q)*64 + lane)*8);
    }
    __syncthreads();

    // ---- one-time: pre = enc_h @ W[:128] + b via 3-term fp16 MFMA (own LSTM only) ----
    v4f pre[4][2];
    {
        const int baseH = isMy ? WMYH_O : WFFH_O;
        const int baseL = isMy ? WMYL_O : WFFL_O;
        const float* bias = isMy ? b_my : b_ff;
        #pragma unroll
        for (int ci = 0; ci < 4; ci++){
            pre[ci][0] = (v4f){0,0,0,0}; pre[ci][1] = (v4f){0,0,0,0};
            #pragma unroll
            for (int q = 0; q < 4; q++){
                int off = (((stripe*4 + ci)*4 + q)*64 + lane)*8;
                v8h bh_ = *(const v8h*)(ws + baseH + off);
                v8h bl_ = *(const v8h*)(ws + baseL + off);
                #pragma unroll
                for (int rt = 0; rt < 2; rt++){
                    v8h ahi = *(const v8h*)&s_hm_hi[0][rt*16 + l15][q*32 + quad*8];
                    v8h alo = *(const v8h*)&s_hm_lo[0][rt*16 + l15][q*32 + quad*8];
                    pre[ci][rt] = __builtin_amdgcn_mfma_f32_16x16x32_f16(ahi, bh_, pre[ci][rt],0,0,0);
                    pre[ci][rt] = __builtin_amdgcn_mfma_f32_16x16x32_f16(ahi, bl_, pre[ci][rt],0,0,0);
                    pre[ci][rt] = __builtin_amdgcn_mfma_f32_16x16x32_f16(alo, bh_, pre[ci][rt],0,0,0);
                }
            }
            float bv = bias[ci*HH + jcol];
            #pragma unroll
            for (int rt = 0; rt < 2; rt++)
                #pragma unroll
                for (int v = 0; v < 4; v++) pre[ci][rt][v] += bv;
        }
    }

    // ---- persistent U B-fragments (own LSTM only: 64 VGPR) ----
    v8h BU[4][4];
    {
        const int ubase = isMy ? UMY_O : UFF_O;
        #pragma unroll
        for (int ci = 0; ci < 4; ci++)
            #pragma unroll
            for (int q = 0; q < 4; q++)
                BU[ci][q] = *(const v8h*)(ws + ubase + (((stripe*4 + ci)*4 + q)*64 + lane)*8);
    }

    int cur = 0;
    for (int t = 0; t < TT; t++){
        const int pb = t & 1;
        const f16 (*rd_hi)[136] = isMy ? s_hm_hi[cur]   : s_hf_hi[cur];
        f16 (*wr_hi)[136]       = isMy ? s_hm_hi[cur^1] : s_hf_hi[cur^1];
        f16 (*wr_lo)[136]       = isMy ? s_hm_lo[cur^1] : s_hf_lo[cur^1];

        // ===== z + gates for own LSTM, rt-split; A = hi only (lo term dropped in-loop) =====
        #pragma unroll
        for (int rt = 0; rt < 2; rt++){
            v4f am[4];
            #pragma unroll
            for (int ci = 0; ci < 4; ci++) am[ci] = pre[ci][rt];
            #pragma unroll
            for (int q = 0; q < 4; q++){
                v8h a_ = *(const v8h*)&rd_hi[rt*16 + l15][q*32 + quad*8];
                #pragma unroll
                for (int ci = 0; ci < 4; ci++)
                    am[ci] = __builtin_amdgcn_mfma_f32_16x16x32_f16(a_, BU[ci][q], am[ci],0,0,0);
            }
            #pragma unroll
            for (int v = 0; v < 4; v++){
                int row = rt*16 + quad*4 + v;
                float z0 = am[0][v], z1 = am[1][v], z2 = am[2][v], z3 = am[3][v];
                if (isMy){
                    v4f c4 = *(const v4f*)&s_c5p[row][0];
                    float c5 = s_c5p[row][4];
                    #pragma unroll
                    for (int k = 0; k < 4; k++){
                        z0 = fmaf(c4[k], wreg[k][0], z0);
                        z1 = fmaf(c4[k], wreg[k][1], z1);
                        z2 = fmaf(c4[k], wreg[k][2], z2);
                        z3 = fmaf(c4[k], wreg[k][3], z3);
                    }
                    z0 = fmaf(c5, wreg[4][0], z0);
                    z1 = fmaf(c5, wreg[4][1], z1);
                    z2 = fmaf(c5, wreg[4][2], z2);
                    z3 = fmaf(c5, wreg[4][3], z3);
                } else {
                    v4f c4 = *(const v4f*)&s_c2p[row][0];
                    #pragma unroll
                    for (int k = 0; k < 2; k++){
                        z0 = fmaf(c4[k], wreg[k][0], z0);
                        z1 = fmaf(c4[k], wreg[k][1], z1);
                        z2 = fmaf(c4[k], wreg[k][2], z2);
                        z3 = fmaf(c4[k], wreg[k][3], z3);
                    }
                }
                float c2 = sigm(z1)*cc[rt*4+v] + sigm(z0)*tanh_(z2);
                cc[rt*4+v] = c2;
                float h = sigm(z3)*tanh_(c2);
                f16 hi = (f16)h;
                wr_hi[row][jcol] = hi;
                wr_lo[row][jcol] = (f16)(h - (float)hi);
            }
        }
        __syncthreads();   // B1: new h visible (drains prev-step output stores)

        // ===== heads (waves 0-9, hi+lo, 1 rt each) / prefetch t+1 (waves 10-15) =====
        if (w < 10){
            const f16 (*Hhi)[136] = hm ? s_hm_hi[cur^1] : s_hf_hi[cur^1];
            const f16 (*Hlo)[136] = hm ? s_hm_lo[cur^1] : s_hf_lo[cur^1];
            v4f a = (v4f){0,0,0,0};
            #pragma unroll
            for (int q = 0; q < 4; q++){
                v8h ahi = *(const v8h*)&Hhi[rth*16 + l15][q*32 + quad*8];
                v8h alo = *(const v8h*)&Hlo[rth*16 + l15][q*32 + quad*8];
                a = __builtin_amdgcn_mfma_f32_16x16x32_f16(ahi, BH[q], a,0,0,0);
                a = __builtin_amdgcn_mfma_f32_16x16x32_f16(alo, BH[q], a,0,0,0);
            }
            if (gc < ncol){
                #pragma unroll
                for (int v = 0; v < 4; v++)
                    s_r[rth*16 + quad*4 + v][rbase + gc] = a[v] + hbias;
            }
        } else {
            int tp = t + 1;
            if (tp < TT){
                int pb2 = tp & 1;
                int tn2 = (tp + 1 < TT) ? tp + 1 : TT - 1;
                for (int i = tid - 640; i < 960; i += 384){
                    if (i < 640){
                        int r = i/20, rem = i - r*20, j = rem/5, k = rem - j*5;
                        s_gum[pb2][r][rem] = gum[((tp*4 + j)*BB + row0 + r)*KC + k];
                    } else if (i < 800){
                        int e = i - 640, r = e/5, k = e - r*5;
                        s_zn[pb2][r][k] = znorm[(tp*BB + row0 + r)*5 + k];
                    } else {
                        int e = i - 800, r = e/5, k = e - r*5;
                        int b = row0 + r;
                        float v = (k==0) ? cond_m[(b*TT + tn2)*2 + 0]
                                : (k==1) ? cond_m[(b*TT + tn2)*2 + 1]
                                : (k==2) ? cond_y[b*TT + tn2]
                                : (k==3) ? cond_f[b*TT + tn2]
                                :          cond_fa[b*TT + tn2];
                        s_nc[pb2][r][k] = v;
                    }
                }
            }
        }
        __syncthreads();   // B2: s_r visible

        // ===== softmax (tid<128) ∥ sampling + next cond (tid 128-255) =====
        if (tid < R*4){
            int r = tid >> 2, g = tid & 3;
            int base = (g==0) ? 0 : (g==1) ? 30 : (g==2) ? 45 : 60;
            float m = s_r[r][base];
            #pragma unroll
            for (int k = 1; k < KC; k++) m = fmaxf(m, s_r[r][base+k]);
            float s = 0.f;
            #pragma unroll
            for (int k = 0; k < KC; k++) s += __expf(s_r[r][base+k] - m);
            s_red[r][2*g] = m; s_red[r][2*g+1] = rcp_(s);
        } else if (tid < 2*R*4){
            int qq = tid - R*4;
            int r = qq >> 2, g = qq & 3;
            const float* Rr = s_r[r];
            int base = (g==0) ? 0 : (g==1) ? 30 : (g==2) ? 45 : 60;
            const float* gg = &s_gum[pb][r][g*5];
            int im = 0; float bv = Rr[base] + gg[0];
            #pragma unroll
            for (int k = 1; k < KC; k++){
                float v = Rr[base+k] + gg[k];
                if (v > bv){ bv = v; im = k; }
            }
            if (g == 0){
                float z1 = s_zn[pb][r][0], z2 = s_zn[pb][r][1];
                float rv   = tanh_(Rr[25 + im]);
                float slon = Rr[5 + im]  + __expf(Rr[10 + im]) * z1;
                float slat = Rr[15 + im] + __expf(Rr[20 + im]) *
                             (rv*z1 + sqrtf(fmaxf(0.f, 1.f - rv*rv))*z2);
                float nm0 = s_nc[pb][r][0], nm1 = s_nc[pb][r][1];
                s_c5p[r][0] = (fabsf(slon - nm0) < AM0) ? slon : nm0;
                s_c5p[r][1] = (fabsf(slat - nm1) < AM1) ? slat : nm1;
            } else if (g == 1){
                float sy = Rr[35 + im] + __expf(Rr[40 + im]) * s_zn[pb][r][2];
                float ny = s_nc[pb][r][2];
                s_c5p[r][2] = (fabsf(sy - ny) < AO) ? sy : ny;
            } else if (g == 2){
                float sf = Rr[50 + im] + __expf(Rr[55 + im]) * s_zn[pb][r][3];
                float nf = s_nc[pb][r][3];
                float cf = (fabsf(sf - nf) < AO) ? sf : nf;
                s_c5p[r][3] = cf; s_c2p[r][0] = cf;
            } else {
                float sfa = Rr[65 + im] + __expf(Rr[70 + im]) * s_zn[pb][r][4];
                float nfa = s_nc[pb][r][4];
                float cfa = (fabsf(sfa - nfa) < AO) ? sfa : nfa;
                s_c5p[r][4] = cfa; s_c2p[r][1] = cfa;
            }
        }
        __syncthreads();   // B3: s_red/s_c5p visible

        // ===== outputs (fp32, s_red-based), 1024 threads — in shadow of z+gates(t+1) =====
        {
            int r  = tid >> 5;          // 0..31
            int q0 = tid & 31;
            const float* Rr = s_r[r];
            int b = row0 + r;
            for (int q = q0; q < 75; q += 32){
                float v; int dst;
                if (q < 30){
                    float x = Rr[q];
                    if (q < 5)       v = __expf(x - s_red[r][0]) * s_red[r][1];
                    else if (q < 10) v = x;
                    else if (q < 15) v = __expf(x);
                    else if (q < 20) v = x;
                    else if (q < 25) v = __expf(x);
                    else             v = tanh_(x);
                    dst = (b*TT + t)*30 + q;
                } else if (q < 45){
                    int q2 = q - 30; float x = Rr[30 + q2];
                    v = (q2 < 5) ? __expf(x - s_red[r][2]) * s_red[r][3]
                                 : (q2 < 10) ? x : __expf(x);
                    dst = GY_OFF + (b*TT + t)*15 + q2;
                } else if (q < 60){
                    int q2 = q - 45; float x = Rr[45 + q2];
                    v = (q2 < 5) ? __expf(x - s_red[r][4]) * s_red[r][5]
                                 : (q2 < 10) ? x : __expf(x);
                    dst = GF_OFF + (b*TT + t)*15 + q2;
                } else {
                    int q2 = q - 60; float x = Rr[60 + q2];
                    v = (q2 < 5) ? __expf(x - s_red[r][6]) * s_red[r][7]
                                 : (q2 < 10) ? x : __expf(x);
                    dst = GFA_OFF + (b*TT + t)*15 + q2;
                }
                out[dst] = v;
            }
        }
        // no end-of-loop barrier: B1 of next step provides ordering
        cur ^= 1;
    }
}

extern "C" void kernel_launch(void* const* d_in, const int* in_sizes, int n_in,
                              void* d_out, int out_size, void* d_ws, size_t ws_size,
                              hipStream_t stream)
{
    (void)in_sizes; (void)n_in; (void)ws_size; (void)out_size;
    const float* cond_m  = (const float*)d_in[0];
    const float* cond_y  = (const float*)d_in[1];
    const float* cond_f  = (const float*)d_in[2];
    const float* cond_fa = (const float*)d_in[3];
    const float* state_h = (const float*)d_in[4];
    const float* state_c = (const float*)d_in[5];
    const float* W_my    = (const float*)d_in[6];
    const float* U_my    = (const float*)d_in[7];
    const float* b_my    = (const float*)d_in[8];
    const float* W_ff    = (const float*)d_in[9];
    const float* U_ff    = (const float*)d_in[10];
    const float* b_ff    = (const float*)d_in[11];
    const float* Wh_my   = (const float*)d_in[12];
    const float* bh_my   = (const float*)d_in[13];
    const float* Wh_ff   = (const float*)d_in[14];
    const float* bh_ff   = (const float*)d_in[15];
    const float* gum     = (const float*)d_in[16];
    const float* znorm   = (const float*)d_in[17];
    f16* ws = (f16*)d_ws;
    float* out = (float*)d_out;

    prep_kernel<<<(PREP_N + 255)/256, 256, 0, stream>>>(U_my, U_ff, W_my, W_ff, Wh_my, Wh_ff, ws);
    decoder_kernel<<<NBLK, NT, 0, stream>>>(
        cond_m, cond_y, cond_f, cond_fa, state_h, state_c,
        W_my, b_my, W_ff, b_ff, bh_my, bh_ff, gum, znorm, ws, out);
}

// Round 10
// 395.505 us; speedup vs baseline: 1.1951x; 1.1321x over previous
//
#include <hip/hip_runtime.h>

#define BB 8192
#define TT 20
#define HH 128
#define H4 512
#define KC 5
#define R 32
#define NT 1024
#define NBLK (BB/R)   // 256 blocks = 1 per CU, 16 waves each

typedef _Float16 f16;
typedef float v4f __attribute__((ext_vector_type(4)));
typedef _Float16 v8h __attribute__((ext_vector_type(8)));

// output segment offsets (elements)
#define GY_OFF (BB*TT*30)
#define GF_OFF (GY_OFF + BB*TT*15)
#define GFA_OFF (GF_OFF + BB*TT*15)

// ws offsets in f16 units
#define UMY_O   0          // U_my fp16 hi, permuted cols (65536)
#define UFF_O   65536
#define WMYH_O  131072     // W_my[:128] fp16 hi, permuted (65536)
#define WMYL_O  196608     // fp16 lo
#define WFFH_O  262144
#define WFFL_O  327680
#define WHMY_O  393216     // Wh_my hi, unpermuted (6144)
#define WHFF_O  399360     // Wh_ff hi (4096)
#define PREP_N  272384

__device__ __forceinline__ float rcp_(float x){ return __builtin_amdgcn_rcpf(x); }
__device__ __forceinline__ float sigm(float x){ return rcp_(1.0f + __expf(-x)); }
__device__ __forceinline__ float tanh_(float x){
    x = __builtin_amdgcn_fmed3f(x, -10.0f, 10.0f);
    float e = __expf(2.0f * x);
    return (e - 1.0f) * rcp_(e + 1.0f);
}

#define AM0 0.3f
#define AM1 0.1f
#define AO  0.3f

// B-frag (16x16x32): lane L holds B[k=(L>>4)*8+jj][n=L&15], jj=0..7.
// elem index e = ((c*4+q)*64 + L)*8 + jj.  U/W col-permutation: tile c -> gate=c&3,
// unit base=((c>>2)<<4), so orig col = (c&3)*128 + ((c>>2)<<4) + (L&15).
__global__ void prep_kernel(const float* __restrict__ U_my, const float* __restrict__ U_ff,
                            const float* __restrict__ W_my, const float* __restrict__ W_ff,
                            const float* __restrict__ Wh_my, const float* __restrict__ Wh_ff,
                            f16* __restrict__ ws)
{
    int t = blockIdx.x * 256 + threadIdx.x;
    if (t >= PREP_N) return;
    if (t < 131072){
        int m = t >> 16, e = t & 65535;
        int jj = e & 7, L = (e >> 3) & 63, q = (e >> 9) & 3, c = e >> 11;
        int k   = q*32 + ((L >> 4) << 3) + jj;
        int col = (c & 3)*HH + ((c >> 2) << 4) + (L & 15);
        float v = (m ? U_ff : U_my)[k*H4 + col];
        ws[(m ? UFF_O : UMY_O) + e] = (f16)v;
    } else if (t < 262144){
        int m = (t - 131072) >> 16, e = t & 65535;
        int jj = e & 7, L = (e >> 3) & 63, q = (e >> 9) & 3, c = e >> 11;
        int k   = q*32 + ((L >> 4) << 3) + jj;
        int col = (c & 3)*HH + ((c >> 2) << 4) + (L & 15);
        float v = (m ? W_ff : W_my)[k*H4 + col];
        f16 hi = (f16)v;
        f16 lo = (f16)(v - (float)hi);
        ws[(m ? WFFH_O : WMYH_O) + e] = hi;
        ws[(m ? WFFL_O : WMYL_O) + e] = lo;
    } else if (t < 262144 + 6144){
        int e = t - 262144;
        int jj = e & 7, L = (e >> 3) & 63, q = (e >> 9) & 3, c = e >> 11;   // c 0..2
        int k   = q*32 + ((L >> 4) << 3) + jj;
        int col = (c << 4) + (L & 15);
        float v = (col < 45) ? Wh_my[k*45 + col] : 0.0f;
        ws[WHMY_O + e] = (f16)v;
    } else {
        int e = t - 262144 - 6144;
        int jj = e & 7, L = (e >> 3) & 63, q = (e >> 9) & 3, c = e >> 11;   // c 0..1
        int k   = q*32 + ((L >> 4) << 3) + jj;
        int col = (c << 4) + (L & 15);
        float v = (col < 30) ? Wh_ff[k*30 + col] : 0.0f;
        ws[WHFF_O + e] = (f16)v;
    }
}

// gate nonlinearity for one rt; k-outer so each W-cond value is read ONCE per rt
template<int NC>
__device__ __forceinline__ void gates_body(
    v4f am[4], const float* __restrict__ cndp, const float* __restrict__ wcp,
    float* __restrict__ cc, f16 (* __restrict__ wr_hi)[136], f16 (* __restrict__ wr_lo)[136],
    int rt, int quad, int jcol)
{
    #pragma unroll
    for (int k = 0; k < NC; k++){
        float w0 = wcp[k*H4 + 0*HH + jcol];
        float w1 = wcp[k*H4 + 1*HH + jcol];
        float w2 = wcp[k*H4 + 2*HH + jcol];
        float w3 = wcp[k*H4 + 3*HH + jcol];
        #pragma unroll
        for (int v = 0; v < 4; v++){
            float cv = cndp[(rt*16 + quad*4 + v)*NC + k];
            am[0][v] = fmaf(cv, w0, am[0][v]);
            am[1][v] = fmaf(cv, w1, am[1][v]);
            am[2][v] = fmaf(cv, w2, am[2][v]);
            am[3][v] = fmaf(cv, w3, am[3][v]);
        }
    }
    #pragma unroll
    for (int v = 0; v < 4; v++){
        int row = rt*16 + quad*4 + v;
        float c2 = sigm(am[1][v])*cc[rt*4+v] + sigm(am[0][v])*tanh_(am[2][v]);
        cc[rt*4+v] = c2;
        float h = sigm(am[3][v])*tanh_(c2);
        f16 hi = (f16)h;
        wr_hi[row][jcol] = hi;
        wr_lo[row][jcol] = (f16)(h - (float)hi);
    }
}

__global__ __launch_bounds__(NT, 4) void decoder_kernel(
    const float* __restrict__ cond_m, const float* __restrict__ cond_y,
    const float* __restrict__ cond_f, const float* __restrict__ cond_fa,
    const float* __restrict__ state_h, const float* __restrict__ state_c,
    const float* __restrict__ W_my, const float* __restrict__ b_my,
    const float* __restrict__ W_ff, const float* __restrict__ b_ff,
    const float* __restrict__ bh_my, const float* __restrict__ bh_ff,
    const float* __restrict__ gum, const float* __restrict__ znorm,
    const f16* __restrict__ ws, float* __restrict__ out)
{
    __shared__ f16 s_hm_hi[2][R][136], s_hm_lo[2][R][136];   // double-buffered h
    __shared__ f16 s_hf_hi[2][R][136], s_hf_lo[2][R][136];
    __shared__ float s_wcm[5][H4], s_wcf[2][H4];             // cond rows of W
    __shared__ float s_r[R][76];
    __shared__ float s_red[R][8];
    __shared__ float s_c5[R][5], s_c2[R][2];
    __shared__ float s_gum[2][R][20], s_zn[2][R][5], s_nc[2][R][5];

    const int tid  = threadIdx.x;
    const int lane = tid & 63, w = tid >> 6;           // 16 waves
    const int quad = lane >> 4, l15 = lane & 15;
    const int stripe = w & 7;                          // unit stripe for this wave
    const int isMy = (w < 8);                          // waves 0-7: my-LSTM, 8-15: ff-LSTM
    const int jcol = (stripe << 4) + l15;
    const int row0 = blockIdx.x * R;

    // ---- init LDS ----
    for (int p = tid; p < R*HH; p += NT){
        int r = p >> 7, k = p & 127;
        float v = state_h[(row0 + r)*HH + k];
        f16 hi = (f16)v, lo = (f16)(v - (float)hi);
        s_hm_hi[0][r][k] = hi; s_hm_lo[0][r][k] = lo;
        s_hf_hi[0][r][k] = hi; s_hf_lo[0][r][k] = lo;
    }
    for (int p = tid; p < 5*H4; p += NT) s_wcm[p >> 9][p & 511] = W_my[(HH + (p >> 9))*H4 + (p & 511)];
    for (int p = tid; p < 2*H4; p += NT) s_wcf[p >> 9][p & 511] = W_ff[(HH + (p >> 9))*H4 + (p & 511)];
    if (tid < R){
        int b = row0 + tid;
        float m0 = cond_m[(b*TT)*2 + 0], m1 = cond_m[(b*TT)*2 + 1];
        float y0 = cond_y[b*TT], f0 = cond_f[b*TT], fa0 = cond_fa[b*TT];
        s_c5[tid][0]=m0; s_c5[tid][1]=m1; s_c5[tid][2]=y0; s_c5[tid][3]=f0; s_c5[tid][4]=fa0;
        s_c2[tid][0]=f0; s_c2[tid][1]=fa0;
    }
    // initial sampling-input prefetch for t=0 into buf 0
    for (int i = tid; i < 960; i += NT){
        if (i < 640){
            int r = i/20, rem = i - r*20, j = rem/5, k = rem - j*5;
            s_gum[0][r][rem] = gum[(j*BB + row0 + r)*KC + k];
        } else if (i < 800){
            int e = i - 640, r = e/5, k = e - r*5;
            s_zn[0][r][k] = znorm[(row0 + r)*5 + k];
        } else {
            int e = i - 800, r = e/5, k = e - r*5;
            int b = row0 + r; int tn = 1;
            float v = (k==0) ? cond_m[(b*TT + tn)*2 + 0]
                    : (k==1) ? cond_m[(b*TT + tn)*2 + 1]
                    : (k==2) ? cond_y[b*TT + tn]
                    : (k==3) ? cond_f[b*TT + tn]
                    :          cond_fa[b*TT + tn];
            s_nc[0][r][k] = v;
        }
    }

    // c-state in registers: cc[rt*4+v] -> row rt*16+quad*4+v, unit jcol (wave-exclusive)
    float cc[8];
    #pragma unroll
    for (int rt = 0; rt < 2; rt++)
        #pragma unroll
        for (int v = 0; v < 4; v++)
            cc[rt*4+v] = state_c[(row0 + rt*16 + quad*4 + v)*HH + jcol];
    __syncthreads();

    // ---- one-time: pre = enc_h @ W[:128] + b via 3-term fp16 MFMA (own LSTM only) ----
    v4f pre[4][2];
    {
        const int baseH = isMy ? WMYH_O : WFFH_O;
        const int baseL = isMy ? WMYL_O : WFFL_O;
        const float* bias = isMy ? b_my : b_ff;
        #pragma unroll
        for (int ci = 0; ci < 4; ci++){
            pre[ci][0] = (v4f){0,0,0,0}; pre[ci][1] = (v4f){0,0,0,0};
            #pragma unroll
            for (int q = 0; q < 4; q++){
                int off = (((stripe*4 + ci)*4 + q)*64 + lane)*8;
                v8h bh_ = *(const v8h*)(ws + baseH + off);
                v8h bl_ = *(const v8h*)(ws + baseL + off);
                #pragma unroll
                for (int rt = 0; rt < 2; rt++){
                    v8h ahi = *(const v8h*)&s_hm_hi[0][rt*16 + l15][q*32 + quad*8];
                    v8h alo = *(const v8h*)&s_hm_lo[0][rt*16 + l15][q*32 + quad*8];
                    pre[ci][rt] = __builtin_amdgcn_mfma_f32_16x16x32_f16(ahi, bh_, pre[ci][rt],0,0,0);
                    pre[ci][rt] = __builtin_amdgcn_mfma_f32_16x16x32_f16(ahi, bl_, pre[ci][rt],0,0,0);
                    pre[ci][rt] = __builtin_amdgcn_mfma_f32_16x16x32_f16(alo, bh_, pre[ci][rt],0,0,0);
                }
            }
            float bv = bias[ci*HH + jcol];
            #pragma unroll
            for (int rt = 0; rt < 2; rt++)
                #pragma unroll
                for (int v = 0; v < 4; v++) pre[ci][rt][v] += bv;
        }
    }

    // ---- persistent U B-fragments (own LSTM only: 64 VGPR) ----
    v8h BU[4][4];
    {
        const int ubase = isMy ? UMY_O : UFF_O;
        #pragma unroll
        for (int ci = 0; ci < 4; ci++)
            #pragma unroll
            for (int q = 0; q < 4; q++)
                BU[ci][q] = *(const v8h*)(ws + ubase + (((stripe*4 + ci)*4 + q)*64 + lane)*8);
    }

    // wave-uniform gate-phase pointers
    const float* wcp  = isMy ? &s_wcm[0][0] : &s_wcf[0][0];
    const float* cndp = isMy ? &s_c5[0][0]  : &s_c2[0][0];

    int cur = 0;
    for (int t = 0; t < TT; t++){
        const int pb = t & 1;
        const f16 (*rd_hi)[136] = isMy ? s_hm_hi[cur]   : s_hf_hi[cur];
        f16 (*wr_hi)[136]       = isMy ? s_hm_hi[cur^1] : s_hf_hi[cur^1];
        f16 (*wr_lo)[136]       = isMy ? s_hm_lo[cur^1] : s_hf_lo[cur^1];

        // ===== z + gates for own LSTM, rt-split; z uses hi-only A (lo dropped — verified
        //       numerically safe in r9: absmax unchanged at 0.015625) =====
        #pragma unroll
        for (int rt = 0; rt < 2; rt++){
            v4f am[4];
            #pragma unroll
            for (int ci = 0; ci < 4; ci++) am[ci] = pre[ci][rt];
            #pragma unroll
            for (int q = 0; q < 4; q++){
                v8h ahi = *(const v8h*)&rd_hi[rt*16 + l15][q*32 + quad*8];
                #pragma unroll
                for (int ci = 0; ci < 4; ci++)
                    am[ci] = __builtin_amdgcn_mfma_f32_16x16x32_f16(ahi, BU[ci][q], am[ci],0,0,0);
            }
            if (isMy) gates_body<5>(am, cndp, wcp, cc, wr_hi, wr_lo, rt, quad, jcol);
            else      gates_body<2>(am, cndp, wcp, cc, wr_hi, wr_lo, rt, quad, jcol);
        }
        __syncthreads();   // B1: new h visible (drains prev-step output stores)

        // ===== heads (waves 0-9, hi+lo, 1 rt each) / prefetch t+1 (waves 10-15) =====
        if (w < 10){
            int w5 = w >> 1, rth = w & 1;
            int hm = (w5 < 3);
            const f16 (*Hhi)[136] = hm ? s_hm_hi[cur^1] : s_hf_hi[cur^1];
            const f16 (*Hlo)[136] = hm ? s_hm_lo[cur^1] : s_hf_lo[cur^1];
            int base  = hm ? WHMY_O : WHFF_O;
            int ch    = hm ? w5 : w5 - 3;
            int ncol  = hm ? 45 : 30;
            int rbase = hm ? 0 : 45;
            const float* bh = hm ? bh_my : bh_ff;
            v4f a = (v4f){0,0,0,0};
            #pragma unroll
            for (int q = 0; q < 4; q++){
                v8h BHq = *(const v8h*)(ws + base + ((ch*4 + q)*64 + lane)*8);
                v8h ahi = *(const v8h*)&Hhi[rth*16 + l15][q*32 + quad*8];
                v8h alo = *(const v8h*)&Hlo[rth*16 + l15][q*32 + quad*8];
                a = __builtin_amdgcn_mfma_f32_16x16x32_f16(ahi, BHq, a,0,0,0);
                a = __builtin_amdgcn_mfma_f32_16x16x32_f16(alo, BHq, a,0,0,0);
            }
            int gc = ch*16 + l15;
            if (gc < ncol){
                float bias = bh[gc];
                #pragma unroll
                for (int v = 0; v < 4; v++)
                    s_r[rth*16 + quad*4 + v][rbase + gc] = a[v] + bias;
            }
        } else {
            int tp = t + 1;
            if (tp < TT){
                int pb2 = tp & 1;
                int tn2 = (tp + 1 < TT) ? tp + 1 : TT - 1;
                for (int i = tid - 640; i < 960; i += 384){
                    if (i < 640){
                        int r = i/20, rem = i - r*20, j = rem/5, k = rem - j*5;
                        s_gum[pb2][r][rem] = gum[((tp*4 + j)*BB + row0 + r)*KC + k];
                    } else if (i < 800){
                        int e = i - 640, r = e/5, k = e - r*5;
                        s_zn[pb2][r][k] = znorm[(tp*BB + row0 + r)*5 + k];
                    } else {
                        int e = i - 800, r = e/5, k = e - r*5;
                        int b = row0 + r;
                        float v = (k==0) ? cond_m[(b*TT + tn2)*2 + 0]
                                : (k==1) ? cond_m[(b*TT + tn2)*2 + 1]
                                : (k==2) ? cond_y[b*TT + tn2]
                                : (k==3) ? cond_f[b*TT + tn2]
                                :          cond_fa[b*TT + tn2];
                        s_nc[pb2][r][k] = v;
                    }
                }
            }
        }
        __syncthreads();   // B2: s_r visible

        // ===== softmax (tid<128) ∥ sampling + next cond (tid 128-255) =====
        if (tid < R*4){
            int r = tid >> 2, g = tid & 3;
            int base = (g==0) ? 0 : (g==1) ? 30 : (g==2) ? 45 : 60;
            float m = s_r[r][base];
            #pragma unroll
            for (int k = 1; k < KC; k++) m = fmaxf(m, s_r[r][base+k]);
            float s = 0.f;
            #pragma unroll
            for (int k = 0; k < KC; k++) s += __expf(s_r[r][base+k] - m);
            s_red[r][2*g] = m; s_red[r][2*g+1] = rcp_(s);
        } else if (tid < 2*R*4){
            int qq = tid - R*4;
            int r = qq >> 2, g = qq & 3;
            const float* Rr = s_r[r];
            int base = (g==0) ? 0 : (g==1) ? 30 : (g==2) ? 45 : 60;
            const float* gg = &s_gum[pb][r][g*5];
            int im = 0; float bv = Rr[base] + gg[0];
            #pragma unroll
            for (int k = 1; k < KC; k++){
                float v = Rr[base+k] + gg[k];
                if (v > bv){ bv = v; im = k; }
            }
            if (g == 0){
                float z1 = s_zn[pb][r][0], z2 = s_zn[pb][r][1];
                float rv   = tanh_(Rr[25 + im]);
                float slon = Rr[5 + im]  + __expf(Rr[10 + im]) * z1;
                float slat = Rr[15 + im] + __expf(Rr[20 + im]) *
                             (rv*z1 + sqrtf(fmaxf(0.f, 1.f - rv*rv))*z2);
                float nm0 = s_nc[pb][r][0], nm1 = s_nc[pb][r][1];
                s_c5[r][0] = (fabsf(slon - nm0) < AM0) ? slon : nm0;
                s_c5[r][1] = (fabsf(slat - nm1) < AM1) ? slat : nm1;
            } else if (g == 1){
                float sy = Rr[35 + im] + __expf(Rr[40 + im]) * s_zn[pb][r][2];
                float ny = s_nc[pb][r][2];
                s_c5[r][2] = (fabsf(sy - ny) < AO) ? sy : ny;
            } else if (g == 2){
                float sf = Rr[50 + im] + __expf(Rr[55 + im]) * s_zn[pb][r][3];
                float nf = s_nc[pb][r][3];
                float cf = (fabsf(sf - nf) < AO) ? sf : nf;
                s_c5[r][3] = cf; s_c2[r][0] = cf;
            } else {
                float sfa = Rr[65 + im] + __expf(Rr[70 + im]) * s_zn[pb][r][4];
                float nfa = s_nc[pb][r][4];
                float cfa = (fabsf(sfa - nfa) < AO) ? sfa : nfa;
                s_c5[r][4] = cfa; s_c2[r][1] = cfa;
            }
        }
        __syncthreads();   // B3: s_red/s_c5 visible

        // ===== outputs (fp32), 1024 threads — in shadow of z+gates(t+1) =====
        {
            int r  = tid >> 5;          // 0..31
            int q0 = tid & 31;
            const float* Rr = s_r[r];
            int b = row0 + r;
            for (int q = q0; q < 75; q += 32){
                float v; int dst;
                if (q < 30){
                    float x = Rr[q];
                    if (q < 5)       v = __expf(x - s_red[r][0]) * s_red[r][1];
                    else if (q < 10) v = x;
                    else if (q < 15) v = __expf(x);
                    else if (q < 20) v = x;
                    else if (q < 25) v = __expf(x);
                    else             v = tanh_(x);
                    dst = (b*TT + t)*30 + q;
                } else if (q < 45){
                    int q2 = q - 30; float x = Rr[30 + q2];
                    v = (q2 < 5) ? __expf(x - s_red[r][2]) * s_red[r][3]
                                 : (q2 < 10) ? x : __expf(x);
                    dst = GY_OFF + (b*TT + t)*15 + q2;
                } else if (q < 60){
                    int q2 = q - 45; float x = Rr[45 + q2];
                    v = (q2 < 5) ? __expf(x - s_red[r][4]) * s_red[r][5]
                                 : (q2 < 10) ? x : __expf(x);
                    dst = GF_OFF + (b*TT + t)*15 + q2;
                } else {
                    int q2 = q - 60; float x = Rr[60 + q2];
                    v = (q2 < 5) ? __expf(x - s_red[r][6]) * s_red[r][7]
                                 : (q2 < 10) ? x : __expf(x);
                    dst = GFA_OFF + (b*TT + t)*15 + q2;
                }
                out[dst] = v;
            }
        }
        // no end-of-loop barrier: B1 of next step provides ordering
        cur ^= 1;
    }
}

extern "C" void kernel_launch(void* const* d_in, const int* in_sizes, int n_in,
                              void* d_out, int out_size, void* d_ws, size_t ws_size,
                              hipStream_t stream)
{
    (void)in_sizes; (void)n_in; (void)ws_size; (void)out_size;
    const float* cond_m  = (const float*)d_in[0];
    const float* cond_y  = (const float*)d_in[1];
    const float* cond_f  = (const float*)d_in[2];
    const float* cond_fa = (const float*)d_in[3];
    const float* state_h = (const float*)d_in[4];
    const float* state_c = (const float*)d_in[5];
    const float* W_my    = (const float*)d_in[6];
    const float* U_my    = (const float*)d_in[7];
    const float* b_my    = (const float*)d_in[8];
    const float* W_ff    = (const float*)d_in[9];
    const float* U_ff    = (const float*)d_in[10];
    const float* b_ff    = (const float*)d_in[11];
    const float* Wh_my   = (const float*)d_in[12];
    const float* bh_my   = (const float*)d_in[13];
    const float* Wh_ff   = (const float*)d_in[14];
    const float* bh_ff   = (const float*)d_in[15];
    const float* gum     = (const float*)d_in[16];
    const float* znorm   = (const float*)d_in[17];
    f16* ws = (f16*)d_ws;
    float* out = (float*)d_out;

    prep_kernel<<<(PREP_N + 255)/256, 256, 0, stream>>>(U_my, U_ff, W_my, W_ff, Wh_my, Wh_ff, ws);
    decoder_kernel<<<NBLK, NT, 0, stream>>>(
        cond_m, cond_y, cond_f, cond_fa, state_h, state_c,
        W_my, b_my, W_ff, b_ff, bh_my, bh_ff, gum, znorm, ws, out);
}